// Round 1
// baseline (11986.521 us; speedup 1.0000x reference)
//
#include <hip/hip_runtime.h>

#define B_ 128
#define T_ 256
#define D_ 512
#define H_ 1024
#define O_ 1024
#define NWG 128
#define NCOL 32   // per-WG gate columns: 4 gates x 8 h-cols

typedef _Float16 f16;
typedef _Float16 f16x8 __attribute__((ext_vector_type(8)));
typedef _Float16 f16x2 __attribute__((ext_vector_type(2)));
typedef float f32x4 __attribute__((ext_vector_type(4)));

// ---- workspace layout (bytes) ----
#define OFF_XH   0ull
#define SZ_XH    33554432ull              // [T][D/8][B][8] f16
#define OFF_WHPK (OFF_XH + SZ_XH)
#define SZ_WHPK  8388608ull               // [NWG][H/8][NCOL][8] f16
#define OFF_WXPK (OFF_WHPK + SZ_WHPK)
#define SZ_WXPK  4194304ull               // [NWG][D/8][NCOL][8] f16
#define OFF_BIAS (OFF_WXPK + SZ_WXPK)
#define SZ_BIAS  16384ull                 // [NWG][NCOL] f32
#define OFF_H    (OFF_BIAS + SZ_BIAS)
#define SZ_H     524288ull                // 2 x [H/8][B][8] f16 (double buffer)
#define OFF_WHPT (OFF_H + SZ_H)
#define SZ_WHPT  4194304ull               // [H][O] f32 (Whp transposed)
#define OFF_BAR  (OFF_WHPT + SZ_WHPT)     // barrier counter

// ---------------- prep kernels ----------------

// x[b][t][d] fp32 -> xh[t][d/8][b][8] f16  (A-fragment friendly: octet-major)
__global__ __launch_bounds__(256, 1)
void pack_x(const float* __restrict__ x, f16* __restrict__ xh)
{
    const int id = blockIdx.x * 256 + threadIdx.x;   // < 128*256*64 = 2^21
    const int doct = id & 63;
    const int t = (id >> 6) & 255;
    const int b = id >> 14;
    const float* src = x + ((size_t)b * T_ + t) * D_ + (doct << 3);
    const float4 v0 = *(const float4*)src;
    const float4 v1 = *(const float4*)(src + 4);
    f16x8 o;
    o[0] = (f16)v0.x; o[1] = (f16)v0.y; o[2] = (f16)v0.z; o[3] = (f16)v0.w;
    o[4] = (f16)v1.x; o[5] = (f16)v1.y; o[6] = (f16)v1.z; o[7] = (f16)v1.w;
    *(f16x8*)(xh + ((((size_t)t << 6) + doct) * B_ + b) * 8) = o;
}

// Wh[g][o][k] fp32 -> whpk[w][koct][n][8] f16, n = g*8 + (o - 8w)
__global__ __launch_bounds__(256, 1)
void pack_wh(const float* __restrict__ Wh, f16* __restrict__ whpk)
{
    const int id = blockIdx.x * 256 + threadIdx.x;   // < 128*128*32 = 524288
    const int n = id & 31;
    const int koct = (id >> 5) & 127;
    const int w = id >> 12;
    const int g = n >> 3;
    const int o = (w << 3) + (n & 7);
    const float* src = Wh + ((size_t)g * H_ + o) * H_ + (koct << 3);
    const float4 v0 = *(const float4*)src;
    const float4 v1 = *(const float4*)(src + 4);
    f16x8 ov;
    ov[0] = (f16)v0.x; ov[1] = (f16)v0.y; ov[2] = (f16)v0.z; ov[3] = (f16)v0.w;
    ov[4] = (f16)v1.x; ov[5] = (f16)v1.y; ov[6] = (f16)v1.z; ov[7] = (f16)v1.w;
    *(f16x8*)(whpk + (size_t)id * 8) = ov;
}

// Wx[g][o][d] fp32 -> wxpk[w][doct][n][8] f16
__global__ __launch_bounds__(256, 1)
void pack_wx(const float* __restrict__ Wx, f16* __restrict__ wxpk)
{
    const int id = blockIdx.x * 256 + threadIdx.x;   // < 128*64*32 = 262144
    const int n = id & 31;
    const int doct = (id >> 5) & 63;
    const int w = id >> 11;
    const int g = n >> 3;
    const int o = (w << 3) + (n & 7);
    const float* src = Wx + ((size_t)g * H_ + o) * D_ + (doct << 3);
    const float4 v0 = *(const float4*)src;
    const float4 v1 = *(const float4*)(src + 4);
    f16x8 ov;
    ov[0] = (f16)v0.x; ov[1] = (f16)v0.y; ov[2] = (f16)v0.z; ov[3] = (f16)v0.w;
    ov[4] = (f16)v1.x; ov[5] = (f16)v1.y; ov[6] = (f16)v1.z; ov[7] = (f16)v1.w;
    *(f16x8*)(wxpk + (size_t)id * 8) = ov;
}

// b[g][o] fp32 -> biasp[w][n] fp32
__global__ __launch_bounds__(256, 1)
void pack_bias(const float* __restrict__ bsrc, float* __restrict__ biasp)
{
    const int id = blockIdx.x * 256 + threadIdx.x;   // < 4096
    const int n = id & 31;
    const int w = id >> 5;
    biasp[id] = bsrc[((size_t)(n >> 3) << 10) + (w << 3) + (n & 7)];
}

// Whp[o][k] fp32 -> whpT[k][o] fp32 (64x64 LDS tile transpose)
__global__ __launch_bounds__(256, 1)
void whp_t(const float* __restrict__ Whp, float* __restrict__ wT)
{
    __shared__ float tile[64][65];
    const int bx = blockIdx.x & 15;   // k-tile
    const int by = blockIdx.x >> 4;   // o-tile
    for (int i = threadIdx.x; i < 4096; i += 256) {
        const int r = i >> 6, c = i & 63;
        tile[r][c] = Whp[((size_t)(by * 64 + r) << 10) + bx * 64 + c];
    }
    __syncthreads();
    for (int i = threadIdx.x; i < 4096; i += 256) {
        const int r = i >> 6, c = i & 63;
        wT[((size_t)(bx * 64 + r) << 10) + by * 64 + c] = tile[c][r];
    }
}

// ---------------- persistent recurrent kernel ----------------
// 128 WGs x 512 threads; WG w owns h-cols [8w, 8w+8) x 4 gates (32 N-cols).
// Weights LDS-resident all 256 steps; h double-buffered fp16 in global.
__global__ __launch_bounds__(512, 1)
void lstm_loop(const f16* __restrict__ xh,
               const f16* __restrict__ whpk,
               const f16* __restrict__ wxpk,
               const float* __restrict__ biasp,
               f16* __restrict__ hbuf,
               int* __restrict__ bar)
{
    __shared__ f16  lds_wh[(H_/8) * NCOL * 8];   // 64 KB
    __shared__ f16  lds_wx[(D_/8) * NCOL * 8];   // 32 KB
    __shared__ float lds_gate[NCOL][B_ + 1];     // 16.5 KB, +1 pad kills bank conflicts
    __shared__ float lds_bias[NCOL];

    const int tid = threadIdx.x;
    const int w = blockIdx.x;

    {   // stage this WG's weight slices into LDS (once)
        const f16x8* s1 = (const f16x8*)(whpk + (size_t)w * (H_/8) * NCOL * 8);
        f16x8* d1 = (f16x8*)lds_wh;
        for (int i = tid; i < (H_/8) * NCOL; i += 512) d1[i] = s1[i];
        const f16x8* s2 = (const f16x8*)(wxpk + (size_t)w * (D_/8) * NCOL * 8);
        f16x8* d2 = (f16x8*)lds_wx;
        for (int i = tid; i < (D_/8) * NCOL; i += 512) d2[i] = s2[i];
        if (tid < NCOL) lds_bias[tid] = biasp[w * NCOL + tid];
    }
    __syncthreads();

    const int lane = tid & 63;
    const int wv = tid >> 6;          // 0..7: wave owns batch rows [16wv,16wv+16)
    const int quad = lane >> 4;
    const int l16 = lane & 15;
    const int mrow = (wv << 4) + l16; // A-operand batch row

    float c0 = 0.f, c1 = 0.f;         // fp32 cell state, register-resident
    int target = 0;

    for (int t = 0; t < T_; ++t) {
        const f16* __restrict__ hr = hbuf + (size_t)(t & 1) * (H_/8) * B_ * 8;
        f16* hw = hbuf + (size_t)((t + 1) & 1) * (H_/8) * B_ * 8;

        f32x4 acc0 = {0.f, 0.f, 0.f, 0.f};
        f32x4 acc1 = {0.f, 0.f, 0.f, 0.f};

        // gates += h_{t-1} @ Wh^T  (K = 1024)
        #pragma unroll 4
        for (int kc = 0; kc < 32; ++kc) {
            const int koct = (kc << 2) + quad;
            f16x8 a  = *(const f16x8*)(hr + (((size_t)koct << 7) + mrow) * 8);
            f16x8 b0 = *(const f16x8*)(lds_wh + ((koct << 5) + l16) * 8);
            f16x8 b1 = *(const f16x8*)(lds_wh + ((koct << 5) + 16 + l16) * 8);
            acc0 = __builtin_amdgcn_mfma_f32_16x16x32_f16(a, b0, acc0, 0, 0, 0);
            acc1 = __builtin_amdgcn_mfma_f32_16x16x32_f16(a, b1, acc1, 0, 0, 0);
        }
        // gates += x_t @ Wx^T  (K = 512), fused — no 512 MB xproj intermediate
        const f16* __restrict__ xt = xh + (size_t)t * (D_/8) * B_ * 8;
        #pragma unroll 4
        for (int kc = 0; kc < 16; ++kc) {
            const int koct = (kc << 2) + quad;
            f16x8 a  = *(const f16x8*)(xt + (((size_t)koct << 7) + mrow) * 8);
            f16x8 b0 = *(const f16x8*)(lds_wx + ((koct << 5) + l16) * 8);
            f16x8 b1 = *(const f16x8*)(lds_wx + ((koct << 5) + 16 + l16) * 8);
            acc0 = __builtin_amdgcn_mfma_f32_16x16x32_f16(a, b0, acc0, 0, 0, 0);
            acc1 = __builtin_amdgcn_mfma_f32_16x16x32_f16(a, b1, acc1, 0, 0, 0);
        }

        // stage gate pre-activations to LDS (C-layout: row=quad*4+r, col=l16)
        {
            const int rbase = (wv << 4) + (quad << 2);
            #pragma unroll
            for (int r = 0; r < 4; ++r) {
                lds_gate[l16][rbase + r]      = acc0[r];
                lds_gate[16 + l16][rbase + r] = acc1[r];
            }
        }
        __syncthreads();

        // LSTM elementwise update; thread owns 2 (b,oo) pairs, c stays fp32 in regs
        {
            const int idx0 = tid << 1;
            f16 hv[2];
            #pragma unroll
            for (int i = 0; i < 2; ++i) {
                const int idx = idx0 + i;
                const int bb = idx >> 3;
                const int oo = idx & 7;
                const float gi = lds_gate[oo][bb]      + lds_bias[oo];
                const float gf = lds_gate[8 + oo][bb]  + lds_bias[8 + oo];
                const float gg = lds_gate[16 + oo][bb] + lds_bias[16 + oo];
                const float go = lds_gate[24 + oo][bb] + lds_bias[24 + oo];
                const float it = 1.0f / (1.0f + __expf(-gi));
                const float ft = 1.0f / (1.0f + __expf(-gf));
                const float eg = __expf(2.0f * gg);
                const float gt = 1.0f - 2.0f / (eg + 1.0f);   // tanh, inf-safe
                const float ot = 1.0f / (1.0f + __expf(-go));
                float c = (i == 0) ? c0 : c1;
                c = ft * c + it * gt;
                if (i == 0) c0 = c; else c1 = c;
                const float ec = __expf(2.0f * c);
                const float tc = 1.0f - 2.0f / (ec + 1.0f);   // tanh(c), inf-safe
                hv[i] = (f16)(ot * tc);
            }
            // hw[w-octet][b][oo]: contiguous 4B per thread, coalesced
            *(f16x2*)(hw + ((size_t)w << 10) + idx0) = *(f16x2*)hv;
        }

        // grid barrier: release h, arrive, spin, acquire
        __threadfence();
        __syncthreads();
        target += NWG;
        if (tid == 0) {
            __hip_atomic_fetch_add(bar, 1, __ATOMIC_ACQ_REL, __HIP_MEMORY_SCOPE_AGENT);
            while (__hip_atomic_load(bar, __ATOMIC_RELAXED, __HIP_MEMORY_SCOPE_AGENT) < target) {
                __builtin_amdgcn_s_sleep(2);
            }
        }
        __syncthreads();
        __threadfence();
    }
}

// ---------------- finale: logits = h_T @ Whp^T + bhp; softmax ----------------
__global__ __launch_bounds__(256, 1)
void finale(const f16* __restrict__ hbuf,   // buffer 0 = h_T (T even)
            const float* __restrict__ whpT,
            const float* __restrict__ bhp,
            float* __restrict__ outp)
{
    __shared__ float hrow[H_];
    __shared__ float red[16];
    const int tid = threadIdx.x;
    const int b = blockIdx.x;

    if (tid < H_/8) {
        f16x8 v = *(const f16x8*)(hbuf + (((size_t)tid << 7) + b) * 8);
        #pragma unroll
        for (int j = 0; j < 8; ++j) hrow[(tid << 3) + j] = (float)v[j];
    }
    __syncthreads();

    float lg0 = bhp[tid], lg1 = bhp[tid + 256], lg2 = bhp[tid + 512], lg3 = bhp[tid + 768];
    for (int k = 0; k < H_; ++k) {
        const float hv = hrow[k];
        const float* wr = whpT + ((size_t)k << 10);
        lg0 = fmaf(hv, wr[tid],       lg0);
        lg1 = fmaf(hv, wr[tid + 256], lg1);
        lg2 = fmaf(hv, wr[tid + 512], lg2);
        lg3 = fmaf(hv, wr[tid + 768], lg3);
    }

    const int lane = tid & 63, wv = tid >> 6;
    float mx = fmaxf(fmaxf(lg0, lg1), fmaxf(lg2, lg3));
    for (int off = 32; off > 0; off >>= 1) mx = fmaxf(mx, __shfl_down(mx, off, 64));
    if (lane == 0) red[wv] = mx;
    __syncthreads();
    mx = fmaxf(fmaxf(red[0], red[1]), fmaxf(red[2], red[3]));

    const float e0 = __expf(lg0 - mx), e1 = __expf(lg1 - mx);
    const float e2 = __expf(lg2 - mx), e3 = __expf(lg3 - mx);
    float s = e0 + e1 + e2 + e3;
    for (int off = 32; off > 0; off >>= 1) s += __shfl_down(s, off, 64);
    if (lane == 0) red[8 + wv] = s;
    __syncthreads();
    s = red[8] + red[9] + red[10] + red[11];
    const float inv = 1.0f / s;

    float* op = outp + ((size_t)b << 10);
    op[tid]       = e0 * inv;
    op[tid + 256] = e1 * inv;
    op[tid + 512] = e2 * inv;
    op[tid + 768] = e3 * inv;
}

// ---------------- launch ----------------
extern "C" void kernel_launch(void* const* d_in, const int* in_sizes, int n_in,
                              void* d_out, int out_size, void* d_ws, size_t ws_size,
                              hipStream_t stream)
{
    const float* x    = (const float*)d_in[0];
    const float* Wx   = (const float*)d_in[1];
    const float* Wh   = (const float*)d_in[2];
    const float* bias = (const float*)d_in[3];
    const float* Whp  = (const float*)d_in[4];
    const float* bhp  = (const float*)d_in[5];

    char* ws = (char*)d_ws;
    f16*   xh    = (f16*)(ws + OFF_XH);
    f16*   whpk  = (f16*)(ws + OFF_WHPK);
    f16*   wxpk  = (f16*)(ws + OFF_WXPK);
    float* biasp = (float*)(ws + OFF_BIAS);
    f16*   hbuf  = (f16*)(ws + OFF_H);
    float* whpT  = (float*)(ws + OFF_WHPT);
    int*   bar   = (int*)(ws + OFF_BAR);

    hipMemsetAsync(ws + OFF_H, 0, SZ_H, stream);      // h0 = 0 (both buffers)
    hipMemsetAsync(ws + OFF_BAR, 0, 256, stream);     // barrier counter = 0

    pack_x   <<<8192, 256, 0, stream>>>(x, xh);
    pack_wh  <<<2048, 256, 0, stream>>>(Wh, whpk);
    pack_wx  <<<1024, 256, 0, stream>>>(Wx, wxpk);
    pack_bias<<<16,   256, 0, stream>>>(bias, biasp);
    whp_t    <<<256,  256, 0, stream>>>(Whp, whpT);

    lstm_loop<<<NWG, 512, 0, stream>>>(xh, whpk, wxpk, biasp, hbuf, bar);
    finale   <<<B_,  256, 0, stream>>>(hbuf, whpT, bhp, (float*)d_out);
}

// Round 2
// 2702.970 us; speedup vs baseline: 4.4346x; 4.4346x over previous
//
#include <hip/hip_runtime.h>

#define B_ 128
#define T_ 256
#define D_ 512
#define H_ 1024
#define O_ 1024
#define NWG 128
#define NCOL 32   // per-WG gate columns: 4 gates x 8 h-cols

typedef _Float16 f16;
typedef _Float16 f16x8 __attribute__((ext_vector_type(8)));
typedef float f32x4 __attribute__((ext_vector_type(4)));

// ---- workspace layout (bytes) ----
#define OFF_XH   0ull
#define SZ_XH    33554432ull              // [T][D/8][B][8] f16
#define OFF_WHPK (OFF_XH + SZ_XH)
#define SZ_WHPK  8388608ull               // [NWG][H/8][NCOL][8] f16
#define OFF_WXPK (OFF_WHPK + SZ_WHPK)
#define SZ_WXPK  4194304ull               // [NWG][D/8][NCOL][8] f16
#define OFF_BIAS (OFF_WXPK + SZ_WXPK)
#define SZ_BIAS  16384ull                 // [NWG][NCOL] f32
#define OFF_H    (OFF_BIAS + SZ_BIAS)
#define SZ_H     524288ull                // 2 x [H/8][B][8] f16 (double buffer)
#define OFF_WHPT (OFF_H + SZ_H)
#define SZ_WHPT  4194304ull               // [H][O] f32 (Whp transposed)
#define OFF_BAR  (OFF_WHPT + SZ_WHPT)     // barrier counter

// coherent (sc0 sc1 -> Infinity-Cache) 16B h-load as two 8B relaxed agent atomics
__device__ __forceinline__ f16x8 ld_h16(const f16* p)
{
    union { unsigned long long u[2]; f16x8 v; } r;
    const unsigned long long* q = (const unsigned long long*)p;
    r.u[0] = __hip_atomic_load(q,     __ATOMIC_RELAXED, __HIP_MEMORY_SCOPE_AGENT);
    r.u[1] = __hip_atomic_load(q + 1, __ATOMIC_RELAXED, __HIP_MEMORY_SCOPE_AGENT);
    return r.v;
}

// ---------------- prep kernels ----------------

// x[b][t][d] fp32 -> xh[t][d/8][b][8] f16  (A-fragment friendly: octet-major)
__global__ __launch_bounds__(256, 1)
void pack_x(const float* __restrict__ x, f16* __restrict__ xh)
{
    const int id = blockIdx.x * 256 + threadIdx.x;   // < 128*256*64 = 2^21
    const int doct = id & 63;
    const int t = (id >> 6) & 255;
    const int b = id >> 14;
    const float* src = x + ((size_t)b * T_ + t) * D_ + (doct << 3);
    const float4 v0 = *(const float4*)src;
    const float4 v1 = *(const float4*)(src + 4);
    f16x8 o;
    o[0] = (f16)v0.x; o[1] = (f16)v0.y; o[2] = (f16)v0.z; o[3] = (f16)v0.w;
    o[4] = (f16)v1.x; o[5] = (f16)v1.y; o[6] = (f16)v1.z; o[7] = (f16)v1.w;
    *(f16x8*)(xh + ((((size_t)t << 6) + doct) * B_ + b) * 8) = o;
}

// Wh[g][o][k] fp32 -> whpk[w][koct][n][8] f16, n = g*8 + (o - 8w)
__global__ __launch_bounds__(256, 1)
void pack_wh(const float* __restrict__ Wh, f16* __restrict__ whpk)
{
    const int id = blockIdx.x * 256 + threadIdx.x;   // < 128*128*32 = 524288
    const int n = id & 31;
    const int koct = (id >> 5) & 127;
    const int w = id >> 12;
    const int g = n >> 3;
    const int o = (w << 3) + (n & 7);
    const float* src = Wh + ((size_t)g * H_ + o) * H_ + (koct << 3);
    const float4 v0 = *(const float4*)src;
    const float4 v1 = *(const float4*)(src + 4);
    f16x8 ov;
    ov[0] = (f16)v0.x; ov[1] = (f16)v0.y; ov[2] = (f16)v0.z; ov[3] = (f16)v0.w;
    ov[4] = (f16)v1.x; ov[5] = (f16)v1.y; ov[6] = (f16)v1.z; ov[7] = (f16)v1.w;
    *(f16x8*)(whpk + (size_t)id * 8) = ov;
}

// Wx[g][o][d] fp32 -> wxpk[w][doct][n][8] f16
__global__ __launch_bounds__(256, 1)
void pack_wx(const float* __restrict__ Wx, f16* __restrict__ wxpk)
{
    const int id = blockIdx.x * 256 + threadIdx.x;   // < 128*64*32 = 262144
    const int n = id & 31;
    const int doct = (id >> 5) & 63;
    const int w = id >> 11;
    const int g = n >> 3;
    const int o = (w << 3) + (n & 7);
    const float* src = Wx + ((size_t)g * H_ + o) * D_ + (doct << 3);
    const float4 v0 = *(const float4*)src;
    const float4 v1 = *(const float4*)(src + 4);
    f16x8 ov;
    ov[0] = (f16)v0.x; ov[1] = (f16)v0.y; ov[2] = (f16)v0.z; ov[3] = (f16)v0.w;
    ov[4] = (f16)v1.x; ov[5] = (f16)v1.y; ov[6] = (f16)v1.z; ov[7] = (f16)v1.w;
    *(f16x8*)(wxpk + (size_t)id * 8) = ov;
}

// b[g][o] fp32 -> biasp[w][n] fp32
__global__ __launch_bounds__(256, 1)
void pack_bias(const float* __restrict__ bsrc, float* __restrict__ biasp)
{
    const int id = blockIdx.x * 256 + threadIdx.x;   // < 4096
    const int n = id & 31;
    const int w = id >> 5;
    biasp[id] = bsrc[((size_t)(n >> 3) << 10) + (w << 3) + (n & 7)];
}

// Whp[o][k] fp32 -> whpT[k][o] fp32 (64x64 LDS tile transpose)
__global__ __launch_bounds__(256, 1)
void whp_t(const float* __restrict__ Whp, float* __restrict__ wT)
{
    __shared__ float tile[64][65];
    const int bx = blockIdx.x & 15;   // k-tile
    const int by = blockIdx.x >> 4;   // o-tile
    for (int i = threadIdx.x; i < 4096; i += 256) {
        const int r = i >> 6, c = i & 63;
        tile[r][c] = Whp[((size_t)(by * 64 + r) << 10) + bx * 64 + c];
    }
    __syncthreads();
    for (int i = threadIdx.x; i < 4096; i += 256) {
        const int r = i >> 6, c = i & 63;
        wT[((size_t)(bx * 64 + r) << 10) + by * 64 + c] = tile[c][r];
    }
}

// ---------------- persistent recurrent kernel ----------------
// 128 WGs x 512 threads; WG w owns h-cols [8w, 8w+8) x 4 gates (32 N-cols).
// NO agent fences in the hot loop: all cross-XCD traffic (hbuf, bar) goes
// through relaxed agent-scope atomics (sc0 sc1 -> coherent at Infinity Cache).
__global__ __launch_bounds__(512, 1)
void lstm_loop(const f16* __restrict__ xh,
               const f16* __restrict__ whpk,
               const f16* __restrict__ wxpk,
               const float* __restrict__ biasp,
               f16* __restrict__ hbuf,
               int* __restrict__ bar)
{
    __shared__ f16  lds_wh[(H_/8) * NCOL * 8];   // 64 KB
    __shared__ f16  lds_wx[(D_/8) * NCOL * 8];   // 32 KB
    __shared__ float lds_gate[NCOL][B_ + 1];     // 16.5 KB, +1 pad kills bank conflicts
    __shared__ float lds_bias[NCOL];

    const int tid = threadIdx.x;
    const int w = blockIdx.x;

    {   // stage this WG's weight slices into LDS (once)
        const f16x8* s1 = (const f16x8*)(whpk + (size_t)w * (H_/8) * NCOL * 8);
        f16x8* d1 = (f16x8*)lds_wh;
        for (int i = tid; i < (H_/8) * NCOL; i += 512) d1[i] = s1[i];
        const f16x8* s2 = (const f16x8*)(wxpk + (size_t)w * (D_/8) * NCOL * 8);
        f16x8* d2 = (f16x8*)lds_wx;
        for (int i = tid; i < (D_/8) * NCOL; i += 512) d2[i] = s2[i];
        if (tid < NCOL) lds_bias[tid] = biasp[w * NCOL + tid];
    }
    __syncthreads();

    const int lane = tid & 63;
    const int wv = tid >> 6;          // 0..7: wave owns batch rows [16wv,16wv+16)
    const int quad = lane >> 4;
    const int l16 = lane & 15;
    const int mrow = (wv << 4) + l16; // A-operand batch row

    float c0 = 0.f, c1 = 0.f;         // fp32 cell state, register-resident
    int tgt = 0;

    for (int t = 0; t < T_; ++t) {
        const f16* __restrict__ hr = hbuf + (size_t)(t & 1) * (H_/8) * B_ * 8;
        f16* hw = hbuf + (size_t)((t + 1) & 1) * (H_/8) * B_ * 8;

        f32x4 acc0 = {0.f, 0.f, 0.f, 0.f};
        f32x4 acc1 = {0.f, 0.f, 0.f, 0.f};

        // ---- x-GEMM first: independent of h_{t-1}, hides barrier latency ----
        const f16* __restrict__ xt = xh + (size_t)t * (D_/8) * B_ * 8;
        #pragma unroll 4
        for (int kc = 0; kc < 16; ++kc) {
            const int koct = (kc << 2) + quad;
            f16x8 a  = *(const f16x8*)(xt + (((size_t)koct << 7) + mrow) * 8);
            f16x8 b0 = *(const f16x8*)(lds_wx + ((koct << 5) + l16) * 8);
            f16x8 b1 = *(const f16x8*)(lds_wx + ((koct << 5) + 16 + l16) * 8);
            acc0 = __builtin_amdgcn_mfma_f32_16x16x32_f16(a, b0, acc0, 0, 0, 0);
            acc1 = __builtin_amdgcn_mfma_f32_16x16x32_f16(a, b1, acc1, 0, 0, 0);
        }

        // ---- wait for h_{t-1} to be published (skip at t=0: h0 = 0) ----
        if (t) {
            if (tid == 0) {
                while (__hip_atomic_load(bar, __ATOMIC_RELAXED, __HIP_MEMORY_SCOPE_AGENT) < tgt)
                    __builtin_amdgcn_s_sleep(1);
            }
            __syncthreads();
        }

        // ---- h-GEMM (K = 1024), coherent loads, hand double-buffered ----
        {
            f16x8 A0[8], A1[8];
#define LOADG(A, g)                                                         \
            _Pragma("unroll")                                               \
            for (int kc = 0; kc < 8; ++kc) {                                \
                const int koct = ((g) << 5) + (kc << 2) + quad;             \
                A[kc] = ld_h16(hr + (((size_t)koct << 7) + mrow) * 8);      \
            }
#define COMPG(A, g)                                                         \
            _Pragma("unroll")                                               \
            for (int kc = 0; kc < 8; ++kc) {                                \
                const int koct = ((g) << 5) + (kc << 2) + quad;             \
                f16x8 b0 = *(const f16x8*)(lds_wh + ((koct << 5) + l16) * 8);      \
                f16x8 b1 = *(const f16x8*)(lds_wh + ((koct << 5) + 16 + l16) * 8); \
                acc0 = __builtin_amdgcn_mfma_f32_16x16x32_f16(A[kc], b0, acc0, 0, 0, 0); \
                acc1 = __builtin_amdgcn_mfma_f32_16x16x32_f16(A[kc], b1, acc1, 0, 0, 0); \
            }
            LOADG(A0, 0)
            LOADG(A1, 1)
            COMPG(A0, 0)
            LOADG(A0, 2)
            COMPG(A1, 1)
            LOADG(A1, 3)
            COMPG(A0, 2)
            COMPG(A1, 3)
#undef LOADG
#undef COMPG
        }

        // stage gate pre-activations to LDS (C-layout: row=quad*4+r, col=l16)
        {
            const int rbase = (wv << 4) + (quad << 2);
            #pragma unroll
            for (int r = 0; r < 4; ++r) {
                lds_gate[l16][rbase + r]      = acc0[r];
                lds_gate[16 + l16][rbase + r] = acc1[r];
            }
        }
        __syncthreads();

        // LSTM elementwise update; thread owns 2 (b,oo) pairs, c stays fp32 in regs
        {
            const int idx0 = tid << 1;
            union { f16 h[2]; unsigned int u; } sv;
            #pragma unroll
            for (int i = 0; i < 2; ++i) {
                const int idx = idx0 + i;
                const int bb = idx >> 3;
                const int oo = idx & 7;
                const float gi = lds_gate[oo][bb]      + lds_bias[oo];
                const float gf = lds_gate[8 + oo][bb]  + lds_bias[8 + oo];
                const float gg = lds_gate[16 + oo][bb] + lds_bias[16 + oo];
                const float go = lds_gate[24 + oo][bb] + lds_bias[24 + oo];
                const float it = 1.0f / (1.0f + __expf(-gi));
                const float ft = 1.0f / (1.0f + __expf(-gf));
                const float eg = __expf(2.0f * gg);
                const float gt = 1.0f - 2.0f / (eg + 1.0f);   // tanh, inf-safe
                const float ot = 1.0f / (1.0f + __expf(-go));
                float c = (i == 0) ? c0 : c1;
                c = ft * c + it * gt;
                if (i == 0) c0 = c; else c1 = c;
                const float ec = __expf(2.0f * c);
                const float tc = 1.0f - 2.0f / (ec + 1.0f);   // tanh(c), inf-safe
                sv.h[i] = (f16)(ot * tc);
            }
            // coherent 4B store (write-through to Infinity Cache), coalesced
            __hip_atomic_store((unsigned int*)(hw + ((size_t)w << 10) + idx0), sv.u,
                               __ATOMIC_RELAXED, __HIP_MEMORY_SCOPE_AGENT);
        }

        // drain own stores to the coherence point, then arrive
        asm volatile("s_waitcnt vmcnt(0)" ::: "memory");
        __syncthreads();
        if (tid == 0)
            __hip_atomic_fetch_add(bar, 1, __ATOMIC_RELAXED, __HIP_MEMORY_SCOPE_AGENT);
        tgt += NWG;
    }
}

// ---------------- finale: logits = h_T @ Whp^T + bhp; softmax ----------------
__global__ __launch_bounds__(256, 1)
void finale(const f16* __restrict__ hbuf,   // buffer 0 = h_T (T even)
            const float* __restrict__ whpT,
            const float* __restrict__ bhp,
            float* __restrict__ outp)
{
    __shared__ float hrow[H_];
    __shared__ float red[16];
    const int tid = threadIdx.x;
    const int b = blockIdx.x;

    if (tid < H_/8) {
        f16x8 v = *(const f16x8*)(hbuf + (((size_t)tid << 7) + b) * 8);
        #pragma unroll
        for (int j = 0; j < 8; ++j) hrow[(tid << 3) + j] = (float)v[j];
    }
    __syncthreads();

    float lg0 = bhp[tid], lg1 = bhp[tid + 256], lg2 = bhp[tid + 512], lg3 = bhp[tid + 768];
    for (int k = 0; k < H_; ++k) {
        const float hv = hrow[k];
        const float* wr = whpT + ((size_t)k << 10);
        lg0 = fmaf(hv, wr[tid],       lg0);
        lg1 = fmaf(hv, wr[tid + 256], lg1);
        lg2 = fmaf(hv, wr[tid + 512], lg2);
        lg3 = fmaf(hv, wr[tid + 768], lg3);
    }

    const int lane = tid & 63, wv = tid >> 6;
    float mx = fmaxf(fmaxf(lg0, lg1), fmaxf(lg2, lg3));
    for (int off = 32; off > 0; off >>= 1) mx = fmaxf(mx, __shfl_down(mx, off, 64));
    if (lane == 0) red[wv] = mx;
    __syncthreads();
    mx = fmaxf(fmaxf(red[0], red[1]), fmaxf(red[2], red[3]));

    const float e0 = __expf(lg0 - mx), e1 = __expf(lg1 - mx);
    const float e2 = __expf(lg2 - mx), e3 = __expf(lg3 - mx);
    float s = e0 + e1 + e2 + e3;
    for (int off = 32; off > 0; off >>= 1) s += __shfl_down(s, off, 64);
    if (lane == 0) red[8 + wv] = s;
    __syncthreads();
    s = red[8] + red[9] + red[10] + red[11];
    const float inv = 1.0f / s;

    float* op = outp + ((size_t)b << 10);
    op[tid]       = e0 * inv;
    op[tid + 256] = e1 * inv;
    op[tid + 512] = e2 * inv;
    op[tid + 768] = e3 * inv;
}

// ---------------- launch ----------------
extern "C" void kernel_launch(void* const* d_in, const int* in_sizes, int n_in,
                              void* d_out, int out_size, void* d_ws, size_t ws_size,
                              hipStream_t stream)
{
    const float* x    = (const float*)d_in[0];
    const float* Wx   = (const float*)d_in[1];
    const float* Wh   = (const float*)d_in[2];
    const float* bias = (const float*)d_in[3];
    const float* Whp  = (const float*)d_in[4];
    const float* bhp  = (const float*)d_in[5];

    char* ws = (char*)d_ws;
    f16*   xh    = (f16*)(ws + OFF_XH);
    f16*   whpk  = (f16*)(ws + OFF_WHPK);
    f16*   wxpk  = (f16*)(ws + OFF_WXPK);
    float* biasp = (float*)(ws + OFF_BIAS);
    f16*   hbuf  = (f16*)(ws + OFF_H);
    float* whpT  = (float*)(ws + OFF_WHPT);
    int*   bar   = (int*)(ws + OFF_BAR);

    hipMemsetAsync(ws + OFF_H, 0, SZ_H, stream);      // h0 = 0 (both buffers)
    hipMemsetAsync(ws + OFF_BAR, 0, 256, stream);     // barrier counter = 0

    pack_x   <<<8192, 256, 0, stream>>>(x, xh);
    pack_wh  <<<2048, 256, 0, stream>>>(Wh, whpk);
    pack_wx  <<<1024, 256, 0, stream>>>(Wx, wxpk);
    pack_bias<<<16,   256, 0, stream>>>(bias, biasp);
    whp_t    <<<256,  256, 0, stream>>>(Whp, whpT);

    lstm_loop<<<NWG, 512, 0, stream>>>(xh, whpk, wxpk, biasp, hbuf, bar);
    finale   <<<B_,  256, 0, stream>>>(hbuf, whpT, bhp, (float*)d_out);
}